// Round 6
// baseline (2745.908 us; speedup 1.0000x reference)
//
#include <hip/hip_runtime.h>

// Persistent 2-layer LSTM, T=512, B=64, H=512. fp32 in/out, bf16 MFMA.
// Round-1 flag protocol VERBATIM (proven): domains {l} x {4 batch groups},
// 32 col-blocks each, L3 (sc0 sc1) h-rings + per-block flags, depth-8 ring.
// NEW: (1) weights live in LDS (128KB/block) -- re-read per step via
// ds_read_b128 (~12cy, no L2 traffic, immune to asm memory-clobber
// rematerialization; ends the r3/r4/r5 register-pin fight: VGPR demand is
// now ~130, no spills). (2) TWO batch groups per block (grid 128): group
// b's h-load/flag round trips hide under group a's compute; weights shared
// across the pair. Raw s_barrier+lgkmcnt(0) between reduce phases keeps
// b's vmem in flight (no __syncthreads vmcnt drain mid-step).

#define T_SEQ 512

typedef short s16x8 __attribute__((ext_vector_type(8)));
typedef int   i32x4 __attribute__((ext_vector_type(4)));
typedef float f32x4 __attribute__((ext_vector_type(4)));

__device__ __forceinline__ short f2bf(float f) {
    unsigned u = __builtin_bit_cast(unsigned, f);
    unsigned r = (u + 0x7fffu + ((u >> 16) & 1u)) >> 16;   // RNE
    return (short)r;
}
__device__ __forceinline__ float sigf(float x) { return 1.0f / (1.0f + __expf(-x)); }
__device__ __forceinline__ float tanhff(float x) { return 2.0f * sigf(2.0f * x) - 1.0f; }

// ---- setup: cast x (fp32) -> bf16 ----
__global__ __launch_bounds__(256) void xcast_kernel(const float* __restrict__ x,
                                                    short* __restrict__ xb) {
    int i = (blockIdx.x * 256 + threadIdx.x) * 8;
    float4 a = *(const float4*)(x + i);
    float4 b = *(const float4*)(x + i + 4);
    s16x8 v;
    v[0]=f2bf(a.x); v[1]=f2bf(a.y); v[2]=f2bf(a.z); v[3]=f2bf(a.w);
    v[4]=f2bf(b.x); v[5]=f2bf(b.y); v[6]=f2bf(b.z); v[7]=f2bf(b.w);
    *(s16x8*)(xb + i) = v;
}

// ---- setup: pack weights [l][bb][w][g][kk0..7][lane][8] bf16 (r1 layout) ----
__global__ __launch_bounds__(256) void wpack_kernel(const float* __restrict__ Wxh,
                                                    const float* __restrict__ Whh,
                                                    short* __restrict__ wp) {
    int fg = blockIdx.x * 256 + threadIdx.x;        // [0, 524288)
    int lane = fg & 63;
    int kk   = (fg >> 6)  & 7;
    int g    = (fg >> 9)  & 3;
    int w    = (fg >> 11) & 3;
    int bb   = (fg >> 13) & 31;
    int l    = (fg >> 18) & 1;
    int ksrc = w * 128 + (kk & 3) * 32 + (lane >> 4) * 8;
    int jp   = g * 512 + bb * 16 + (lane & 15);
    const float* src = (kk < 4) ? (Wxh + ((size_t)(l * 2048 + jp) * 512 + ksrc))
                                : (Whh + ((size_t)(l * 2048 + jp) * 512 + ksrc));
    float4 a = *(const float4*)src;
    float4 b = *(const float4*)(src + 4);
    s16x8 v;
    v[0]=f2bf(a.x); v[1]=f2bf(a.y); v[2]=f2bf(a.z); v[3]=f2bf(a.w);
    v[4]=f2bf(b.x); v[5]=f2bf(b.y); v[6]=f2bf(b.z); v[7]=f2bf(b.w);
    *(s16x8*)(wp + (size_t)fg * 8) = v;
}

// ---- L3-coherent 4-frag load, issue only (no wait) ----
__device__ __forceinline__ void issue4(i32x4 af[4], const short* base) {
    asm volatile(
        "global_load_dwordx4 %0, %4, off sc0 sc1\n\t"
        "global_load_dwordx4 %1, %4, off offset:64 sc0 sc1\n\t"
        "global_load_dwordx4 %2, %4, off offset:128 sc0 sc1\n\t"
        "global_load_dwordx4 %3, %4, off offset:192 sc0 sc1"
        : "=&v"(af[0]), "=&v"(af[1]), "=&v"(af[2]), "=&v"(af[3])
        : "v"(base) : "memory");
}

// tie: counted vmcnt + reg dependency so MFMAs can't be hoisted above
#define TIE4(AF, N)                                                           \
    asm volatile("s_waitcnt vmcnt(" #N ")"                                    \
                 : "+v"(AF[0]), "+v"(AF[1]), "+v"(AF[2]), "+v"(AF[3])         \
                 :: "memory")
#define TIE8(A1, A2, N)                                                       \
    asm volatile("s_waitcnt vmcnt(" #N ")"                                    \
                 : "+v"(A1[0]), "+v"(A1[1]), "+v"(A1[2]), "+v"(A1[3]),        \
                   "+v"(A2[0]), "+v"(A2[1]), "+v"(A2[2]), "+v"(A2[3])         \
                 :: "memory")

// ---- merged poll over BOTH groups: lanes 0-31 group a, 32-63 group b ----
__device__ __forceinline__ void waitf4(const unsigned* fa_own, const unsigned* fb_own,
                                       const unsigned* fa_oth, const unsigned* fb_oth,
                                       int ta, int tb, int lane) {
    if (ta <= 0 && tb <= 0) return;
    const unsigned* p0 = ((lane < 32) ? fa_own : fb_own) + (lane & 31);
    const unsigned* p1 = ((lane < 32) ? fa_oth : fb_oth) + (lane & 31);
    int v0, v1;
    do {
        asm volatile("global_load_dword %0, %2, off sc0 sc1\n\t"
                     "global_load_dword %1, %3, off sc0 sc1\n\t"
                     "s_waitcnt vmcnt(0)"
                     : "=&v"(v0), "=&v"(v1)
                     : "v"(p0), "v"(p1) : "memory");
    } while (v0 < ta || v1 < tb);
}

// ---- coherent scalar stores ----
__device__ __forceinline__ void sth_l3(short* p, int bits) {
    asm volatile("global_store_short %0, %1, off sc0 sc1" :: "v"(p), "v"(bits) : "memory");
}
__device__ __forceinline__ void stf_l3(unsigned* p, int v) {
    asm volatile("global_store_dword %0, %1, off sc0 sc1" :: "v"(p), "v"(v) : "memory");
}

#define DRAIN() asm volatile("s_waitcnt vmcnt(0)" ::: "memory")

// raw LDS-only barrier: does NOT drain vmcnt (keeps b-loads/stores in flight)
__device__ __forceinline__ void bar_lds() {
    asm volatile("s_waitcnt lgkmcnt(0)" ::: "memory");
    __builtin_amdgcn_sched_barrier(0);
    __builtin_amdgcn_s_barrier();
    asm volatile("" ::: "memory");
}

// MFMA clusters; weights read from LDS (wlds shorts), kkabs = KB + kk
#define MFMA_X(FR, ACC)                                                       \
    _Pragma("unroll") for (int kk = 0; kk < 4; ++kk)                          \
    _Pragma("unroll") for (int g4 = 0; g4 < 4; ++g4)                          \
        ACC[g4] = __builtin_amdgcn_mfma_f32_16x16x32_bf16(                    \
            FR[kk],                                                           \
            *(const s16x8*)(wlds + (wv*16384 + g4*4096 + kk*512 + lane*8)),   \
            ACC[g4], 0, 0, 0);
#define MFMA_H(FR, KB, ACC)                                                   \
    _Pragma("unroll") for (int kk = 0; kk < 4; ++kk)                          \
    _Pragma("unroll") for (int g4 = 0; g4 < 4; ++g4)                          \
        ACC[g4] = __builtin_amdgcn_mfma_f32_16x16x32_bf16(                    \
            __builtin_bit_cast(s16x8, FR[kk]),                                \
            *(const s16x8*)(wlds + (wv*16384 + g4*4096 + ((KB)+kk)*512 + lane*8)), \
            ACC[g4], 0, 0, 0);

// reduce + epilogue for one group (contains write->bar->read)
#define REDEPI(ACC, CREG, HV)                                                 \
    { _Pragma("unroll") for (int g4 = 0; g4 < 4; ++g4)                        \
        _Pragma("unroll") for (int q = 0; q < 4; ++q)                         \
            red[(wv*4+g4)*288 + ((lane>>4)*4+q)*18 + (lane&15)] = ACC[g4][q]; \
      bar_lds();                                                              \
      float cg[4];                                                            \
      _Pragma("unroll") for (int g4 = 0; g4 < 4; ++g4) {                      \
          float s = bsum[g4];                                                 \
          _Pragma("unroll") for (int w = 0; w < 4; ++w)                       \
              s += red[(w*4+g4)*288 + em*18 + ec];                            \
          cg[g4] = s; }                                                       \
      float cn = sigf(cg[1]) * CREG + sigf(cg[0]) * tanhff(cg[2]);            \
      HV = sigf(cg[3]) * tanhff(cn);                                          \
      CREG = cn; }

__global__
__attribute__((amdgpu_flat_work_group_size(256, 256)))
__attribute__((amdgpu_waves_per_eu(1, 1)))
void lstm_persist(
    const short* __restrict__ xb,    // [T][64][512] bf16
    const short* __restrict__ wp,    // packed weights
    short* __restrict__ h0r,         // [8][64][512] bf16 ring
    short* __restrict__ h1r,         // [8][64][512] bf16 ring
    const float* __restrict__ bxh,   // [2][2048]
    const float* __restrict__ bhh,   // [2][2048]
    float* __restrict__ out,         // T*B*H | hT[2,B,H] | cT[2,B,H]
    unsigned* flags) {               // [2 layers][4 groups][32 blocks]

    const int l    = blockIdx.x >> 6;        // layer
    const int gp   = (blockIdx.x >> 5) & 1;  // group pair
    const int bb   = blockIdx.x & 31;        // col block (16 h-cols)
    const int tid  = threadIdx.x;
    const int wv   = tid >> 6;
    const int lane = tid & 63;
    const int ga   = gp * 2, gb = ga + 1;    // the two owned batch groups

    __shared__ __align__(16) short wlds[65536];   // 128 KB weights
    __shared__ float red[4608];                   // 18 KB reduce

    // ---- stage this block's 128KB weight chunk into LDS (layout-preserving) ----
    {
        const short* wsrc = wp + (size_t)(l * 32 + bb) * 65536;
        #pragma unroll
        for (int k = 0; k < 32; ++k) {
            int off = (k * 256 + tid) * 8;
            *(s16x8*)(wlds + off) = *(const s16x8*)(wsrc + off);
        }
    }
    __syncthreads();

    // ---- epilogue constants: thread owns cell (row em, col ej) per group ----
    const int em = tid >> 4;
    const int ec = tid & 15;
    const int ej = bb * 16 + ec;
    float bsum[4];
    #pragma unroll
    for (int g4 = 0; g4 < 4; ++g4)
        bsum[g4] = bxh[l * 2048 + g4 * 512 + ej] + bhh[l * 2048 + g4 * 512 + ej];

    float creg_a = 0.f, creg_b = 0.f, hv_a = 0.f, hv_b = 0.f;

    const int arow    = lane & 15;
    const int acol    = wv * 128 + (lane >> 4) * 8;
    const int aboff_a = (ga * 16 + arow) * 512 + acol;
    const int aboff_b = aboff_a + 8192;           // next group, +16 rows

    const unsigned* fown_a = flags + (l * 4 + ga) * 32;
    const unsigned* fown_b = flags + (l * 4 + gb) * 32;
    const unsigned* foth_a = flags + ((1 - l) * 4 + ga) * 32;
    const unsigned* foth_b = flags + ((1 - l) * 4 + gb) * 32;

    for (int t = 0; t < T_SEQ; ++t) {
        f32x4 acc_a[4], acc_b[4];
        #pragma unroll
        for (int g4 = 0; g4 < 4; ++g4) {
            acc_a[g4] = (f32x4){0.f, 0.f, 0.f, 0.f};
            acc_b[g4] = (f32x4){0.f, 0.f, 0.f, 0.f};
        }

        if (l == 0) {
            // x halves for both groups first (no dependency; hides poll)
            const short* ab = xb + (size_t)t * 32768;
            s16x8 ax[4], bx2[4];
            #pragma unroll
            for (int kk = 0; kk < 4; ++kk) {
                ax[kk]  = *(const s16x8*)(ab + aboff_a + kk * 32);
                bx2[kk] = *(const s16x8*)(ab + aboff_b + kk * 32);
            }
            MFMA_X(ax, acc_a)
            MFMA_X(bx2, acc_b)
            // own domains >= t, l1 backpressure >= t-7 (both groups, one loop)
            waitf4(fown_a, fown_b, foth_a, foth_b, t, t - 7, lane);
            const short* hbase = h0r + (size_t)(t & 7) * 32768;
            i32x4 fa[4], fb[4];
            issue4(fa, hbase + aboff_a);
            issue4(fb, hbase + aboff_b);
            TIE4(fa, 4);                    // a ready, b still in flight
            MFMA_H(fa, 4, acc_a)
            REDEPI(acc_a, creg_a, hv_a)
            sth_l3(h0r + (size_t)((t + 1) & 7) * 32768 + (ga * 16 + em) * 512 + ej,
                   (int)(unsigned short)f2bf(hv_a));
            TIE4(fb, 1);                    // allow h_a store outstanding
            MFMA_H(fb, 4, acc_b)
            bar_lds();                      // a-reads done before b-writes
            REDEPI(acc_b, creg_b, hv_b)
            sth_l3(h0r + (size_t)((t + 1) & 7) * 32768 + (gb * 16 + em) * 512 + ej,
                   (int)(unsigned short)f2bf(hv_b));
        } else {
            // own >= t (h1[t-1]); producer >= t+1 (h0[t]) -- both groups
            waitf4(fown_a, fown_b, foth_a, foth_b, t, t + 1, lane);
            const short* h1base = h1r + (size_t)(t & 7) * 32768;
            const short* h0base = h0r + (size_t)((t + 1) & 7) * 32768;
            i32x4 ra[4], ia[4], rb[4], ib[4];
            issue4(ra, h1base + aboff_a);
            issue4(ia, h0base + aboff_a);
            issue4(rb, h1base + aboff_b);
            issue4(ib, h0base + aboff_b);
            TIE8(ra, ia, 8);                // a's 8 ready, b's 8 in flight
            MFMA_H(ra, 4, acc_a)            // recurrent half (h1)
            MFMA_H(ia, 0, acc_a)            // input half (h0)
            REDEPI(acc_a, creg_a, hv_a)
            sth_l3(h1r + (size_t)((t + 1) & 7) * 32768 + (ga * 16 + em) * 512 + ej,
                   (int)(unsigned short)f2bf(hv_a));
            TIE8(rb, ib, 1);                // allow h_a store outstanding
            MFMA_H(rb, 4, acc_b)
            MFMA_H(ib, 0, acc_b)
            bar_lds();
            REDEPI(acc_b, creg_b, hv_b)
            sth_l3(h1r + (size_t)((t + 1) & 7) * 32768 + (gb * 16 + em) * 512 + ej,
                   (int)(unsigned short)f2bf(hv_b));
        }

        // drain both h stores, join waves, publish both group flags
        DRAIN();
        bar_lds();
        if (tid < 2) {
            unsigned* mf = flags + (l * 4 + ga + tid) * 32 + bb;
            stf_l3(mf, t + 1);
        }
        // out stores off the drain path
        if (l == 1) {
            out[(size_t)t * 32768 + (size_t)(ga * 16 + em) * 512 + ej] = hv_a;
            out[(size_t)t * 32768 + (size_t)(gb * 16 + em) * 512 + ej] = hv_b;
        }
    }

    // final h/c state (both groups)
    size_t base = (size_t)T_SEQ * 32768;
    out[base + (size_t)(l * 64 + ga * 16 + em) * 512 + ej] = hv_a;
    out[base + (size_t)(l * 64 + gb * 16 + em) * 512 + ej] = hv_b;
    out[base + 65536 + (size_t)(l * 64 + ga * 16 + em) * 512 + ej] = creg_a;
    out[base + 65536 + (size_t)(l * 64 + gb * 16 + em) * 512 + ej] = creg_b;
}

extern "C" void kernel_launch(void* const* d_in, const int* in_sizes, int n_in,
                              void* d_out, int out_size, void* d_ws, size_t ws_size,
                              hipStream_t stream) {
    const float* x   = (const float*)d_in[0];
    const float* Wxh = (const float*)d_in[1];
    const float* Whh = (const float*)d_in[2];
    const float* bxh = (const float*)d_in[3];
    const float* bhh = (const float*)d_in[4];
    float* out = (float*)d_out;

    char* ws = (char*)d_ws;
    short*    xb    = (short*)(ws);                     // 33,554,432 B
    short*    wpk   = (short*)(ws + 33554432);          //  8,388,608 B
    short*    h0r   = (short*)(ws + 41943040);          //    524,288 B
    short*    h1r   = (short*)(ws + 42467328);          //    524,288 B
    unsigned* flags = (unsigned*)(ws + 42991616);       //      1,024 B

    // zero rings + flags (ws re-poisoned 0xAA before every timed launch)
    hipMemsetAsync(ws + 41943040, 0, 1049600, stream);

    xcast_kernel<<<dim3(8192), dim3(256), 0, stream>>>(x, xb);
    wpack_kernel<<<dim3(2048), dim3(256), 0, stream>>>(Wxh, Whh, wpk);

    lstm_persist<<<dim3(128), dim3(256), 0, stream>>>(xb, wpk, h0r, h1r,
                                                      bxh, bhh, out, flags);
}